// Round 3
// baseline (228.236 us; speedup 1.0000x reference)
//
#include <hip/hip_runtime.h>
#include <stdint.h>

// Workspace byte offsets (all 128B-aligned regions)
#define OFF_W1  0        // 1024*32 u32 = 128 KB packed sign bits of w1 (784 bits + zero pad)
#define OFF_W2  131072   // 128 KB
#define OFF_W3  262144   // 128 KB
#define OFF_WFC 393216   // 10*32 u32 = 1280 B (padded to 2048)
#define OFF_T1  395264   // 1024 int32 popcount thresholds
#define OFF_T2  399360
#define OFF_T3  403456
#define OFF_SFC 407552   // double: mean|wfc|

#define RWS 16           // batch rows per block in main kernel

// ---------------------------------------------------------------------------
// Prep: one WAVE per output channel. Pack weight sign bits (bit=1 <=> w>=0,
// Brevitas sign(0)=+1) and per-channel integer popcount thresholds in double
// (exact sign decisions): dot = K - 2p ; layer+BN+sign == (p <= Tint[o]).
// ---------------------------------------------------------------------------
__global__ __launch_bounds__(256) void bnn_prep(
    const float* __restrict__ w1, const float* __restrict__ b1, const float* __restrict__ g1,
    const float* __restrict__ be1, const float* __restrict__ m1, const float* __restrict__ v1,
    const float* __restrict__ w2, const float* __restrict__ b2, const float* __restrict__ g2,
    const float* __restrict__ be2, const float* __restrict__ m2, const float* __restrict__ v2,
    const float* __restrict__ w3, const float* __restrict__ b3, const float* __restrict__ g3,
    const float* __restrict__ be3, const float* __restrict__ m3, const float* __restrict__ v3,
    const float* __restrict__ wfc,
    uint32_t* __restrict__ ws)
{
    const int t    = threadIdx.x;
    const int lane = t & 63;
    const int wv   = t >> 6;

    if (blockIdx.x < 768) {
        const int ch = blockIdx.x * 4 + wv;   // 0..3071
        const int l  = ch >> 10;
        const int o  = ch & 1023;
        const float *w, *bb, *g, *be, *m, *v;
        int K; uint32_t* Wp; int* T;
        if (l == 0)      { w=w1; bb=b1; g=g1; be=be1; m=m1; v=v1; K=784;  Wp = ws + OFF_W1/4; T = (int*)(ws + OFF_T1/4); }
        else if (l == 1) { w=w2; bb=b2; g=g2; be=be2; m=m2; v=v2; K=1024; Wp = ws + OFF_W2/4; T = (int*)(ws + OFF_T2/4); }
        else             { w=w3; bb=b3; g=g3; be=be3; m=m3; v=v3; K=1024; Wp = ws + OFF_W3/4; T = (int*)(ws + OFF_T3/4); }

        const float* wr = w + (size_t)o * K;
        double s = 0.0;
        #pragma unroll
        for (int k = 0; k < 16; ++k) {
            const int idx = k * 64 + lane;
            const bool inb = idx < K;
            float wval = inb ? wr[idx] : -1.0f;        // OOB -> bit 0 (zero pad)
            if (inb) s += fabs((double)wval);
            unsigned long long mask = __ballot(inb && (wval >= 0.0f));
            if (lane == 0)
                *(uint64_t*)(Wp + (size_t)o * 32 + 2 * k) = mask;
        }
        #pragma unroll
        for (int off = 32; off > 0; off >>= 1) s += __shfl_down(s, off, 64);
        if (lane == 0) {
            double scale = s / (double)K;                        // mean|w|, > 0
            double r = (double)g[o] / sqrt((double)v[o] + 1e-5); // > 0
            // f = dot*scale*r + (b-m)*r + be >= 0  <=>  dot >= tt  <=>  p <= Td
            double tt = (((double)m[o] - (double)bb[o]) * r - (double)be[o]) / (scale * r);
            double C  = ceil(tt);                                // dot >= C (dot integer)
            double Td = floor(((double)K - C) * 0.5);
            Td = fmax(fmin(Td, 100000.0), -1.0);
            T[o] = (int)Td;
        }
    } else if (wv == 0) {
        // wfc: one wave packs 10 rows of 1024 bits + global mean|wfc| (double)
        uint32_t* Wp = ws + OFF_WFC/4;
        double s = 0.0;
        for (int rr = 0; rr < 10; ++rr) {
            const float* wr = wfc + rr * 1024;
            #pragma unroll
            for (int k = 0; k < 16; ++k) {
                float wval = wr[k * 64 + lane];
                s += fabs((double)wval);
                unsigned long long mask = __ballot(wval >= 0.0f);
                if (lane == 0)
                    *(uint64_t*)(Wp + rr * 32 + 2 * k) = mask;
            }
        }
        #pragma unroll
        for (int off = 32; off > 0; off >>= 1) s += __shfl_down(s, off, 64);
        if (lane == 0)
            *(double*)(ws + OFF_SFC/4) = s / 10240.0;
    }
}

// ---------------------------------------------------------------------------
// Main: fully fused 3 binary layers + FC. Block = 1024 thr (16 waves).
// C=2 channels/thread: thread (group g = t>>9, tg = t&511) owns channels
// tg and tg+512 (W: 64 VGPR register-resident) and processes rows
// [8g, 8g+8). Each A row is read by 512 threads (not 1024) -> LDS
// ds_read_b128 instruction count HALVED vs C=1 (the R2 bottleneck:
// ~12288 b128/CU x 12cyc = 61us; now ~31us).
// Wave w (wavein = w&7) ballots cover channels [64*wavein,+64) and
// [512+64*wavein,+64) -> words 2*wavein and 16+2*wavein of the next buffer.
// ---------------------------------------------------------------------------
__global__ __launch_bounds__(1024, 4) void bnn_main(
    const float* __restrict__ x,
    const uint32_t* __restrict__ ws,
    const float* __restrict__ bfc,
    float* __restrict__ out)
{
    __shared__ alignas(16) uint32_t bufA[RWS][32];
    __shared__ alignas(16) uint32_t bufB[RWS][32];
    const int t      = threadIdx.x;
    const int lane   = t & 63;
    const int wv     = t >> 6;           // 0..15
    const int g      = t >> 9;           // row group 0/1
    const int tg     = t & 511;          // index within group
    const int wavein = wv & 7;           // wave index within group
    const int row0   = blockIdx.x * RWS;

    // ---- pack input bits: wave wv packs row wv. +1 <=> 2x-1>=0 <=> x>=0.5 ----
    {
        const float* xr = x + (size_t)(row0 + wv) * 784;
        #pragma unroll
        for (int k = 0; k < 13; ++k) {
            const int idx = k * 64 + lane;
            const bool bit = (idx < 784) && (xr[idx] >= 0.5f);
            unsigned long long m = __ballot(bit);
            if (lane == 0) *(uint64_t*)(&bufA[wv][2 * k]) = m;
        }
        if (lane == 0) {
            *(uint64_t*)(&bufA[wv][26]) = 0ull;
            *(uint64_t*)(&bufA[wv][28]) = 0ull;
            *(uint64_t*)(&bufA[wv][30]) = 0ull;
        }
    }
    __syncthreads();

    const uint32_t* Wbase[3] = { ws + OFF_W1/4, ws + OFF_W2/4, ws + OFF_W3/4 };
    const int*      Tbase[3] = { (const int*)(ws + OFF_T1/4), (const int*)(ws + OFF_T2/4), (const int*)(ws + OFF_T3/4) };

    uint32_t (*cur)[32] = bufA;
    uint32_t (*nxt)[32] = bufB;

    const int c0 = tg;          // this thread's two channels
    const int c1 = tg + 512;

    for (int l = 0; l < 3; ++l) {
        uint32_t W0[32], W1[32];
        {
            const uint4* p0 = (const uint4*)(Wbase[l] + (size_t)c0 * 32);
            const uint4* p1 = (const uint4*)(Wbase[l] + (size_t)c1 * 32);
            #pragma unroll
            for (int i = 0; i < 8; ++i) { ((uint4*)W0)[i] = p0[i]; ((uint4*)W1)[i] = p1[i]; }
        }
        const int T0 = Tbase[l][c0];
        const int T1 = Tbase[l][c1];

        #pragma unroll 2
        for (int r = 0; r < 8; ++r) {
            const int row = g * 8 + r;
            uint32_t A[32];
            #pragma unroll
            for (int i = 0; i < 8; ++i) ((uint4*)A)[i] = ((const uint4*)cur[row])[i];  // broadcast
            int pa = 0, pb = 0, pc = 0, pd = 0;   // 4 chains for ILP
            #pragma unroll
            for (int i = 0; i < 16; ++i) {
                pa += __popc(A[i]      ^ W0[i]);
                pb += __popc(A[i + 16] ^ W0[i + 16]);
                pc += __popc(A[i]      ^ W1[i]);
                pd += __popc(A[i + 16] ^ W1[i + 16]);
            }
            unsigned long long m0 = __ballot((pa + pb) <= T0);
            unsigned long long m1 = __ballot((pc + pd) <= T1);
            if (lane == 0) {
                *(uint64_t*)(&nxt[row][2 * wavein])      = m0;
                *(uint64_t*)(&nxt[row][16 + 2 * wavein]) = m1;
            }
        }
        __syncthreads();
        uint32_t (*tmp)[32] = cur; cur = nxt; nxt = tmp;
    }

    // ---- final FC: out[b][c] = (1024-2p)*scaleFC + bfc[c], exact integer dot ----
    if (t < RWS * 10) {
        const float sfc = (float)(*(const double*)(ws + OFF_SFC/4));
        const uint32_t* Wfc = ws + OFF_WFC/4;
        const int r = t / 10, ch = t % 10;
        const uint32_t* wrow = Wfc + ch * 32;
        int p = 0;
        #pragma unroll
        for (int i = 0; i < 32; ++i) p += __popc(cur[r][i] ^ wrow[i]);
        const int s = 1024 - 2 * p;
        out[(size_t)(row0 + r) * 10 + ch] = (float)s * sfc + bfc[ch];
    }
}

extern "C" void kernel_launch(void* const* d_in, const int* in_sizes, int n_in,
                              void* d_out, int out_size, void* d_ws, size_t ws_size,
                              hipStream_t stream) {
    const float* x   = (const float*)d_in[0];
    const float* w1  = (const float*)d_in[1];
    const float* b1  = (const float*)d_in[2];
    const float* g1  = (const float*)d_in[3];
    const float* be1 = (const float*)d_in[4];
    const float* m1  = (const float*)d_in[5];
    const float* v1  = (const float*)d_in[6];
    const float* w2  = (const float*)d_in[7];
    const float* b2  = (const float*)d_in[8];
    const float* g2  = (const float*)d_in[9];
    const float* be2 = (const float*)d_in[10];
    const float* m2  = (const float*)d_in[11];
    const float* v2  = (const float*)d_in[12];
    const float* w3  = (const float*)d_in[13];
    const float* b3  = (const float*)d_in[14];
    const float* g3  = (const float*)d_in[15];
    const float* be3 = (const float*)d_in[16];
    const float* m3  = (const float*)d_in[17];
    const float* v3  = (const float*)d_in[18];
    const float* wfc = (const float*)d_in[19];
    const float* bfc = (const float*)d_in[20];
    uint32_t* ws = (uint32_t*)d_ws;
    float* out = (float*)d_out;

    bnn_prep<<<769, 256, 0, stream>>>(w1, b1, g1, be1, m1, v1,
                                      w2, b2, g2, be2, m2, v2,
                                      w3, b3, g3, be3, m3, v3,
                                      wfc, ws);
    bnn_main<<<8192 / RWS, 1024, 0, stream>>>(x, ws, bfc, out);
}

// Round 4
// 196.987 us; speedup vs baseline: 1.1586x; 1.1586x over previous
//
#include <hip/hip_runtime.h>
#include <stdint.h>

// Workspace byte offsets (all 128B-aligned regions)
#define OFF_W1  0        // 1024*32 u32 = 128 KB packed sign bits of w1 (784 bits + zero pad)
#define OFF_W2  131072   // 128 KB
#define OFF_W3  262144   // 128 KB
#define OFF_WFC 393216   // 10*32 u32 = 1280 B (padded to 2048)
#define OFF_T1  395264   // 1024 int32 popcount thresholds
#define OFF_T2  399360
#define OFF_T3  403456
#define OFF_SFC 407552   // double: mean|wfc|

#define RWS 8            // batch rows per block in main kernel (== waves per block)

// ---------------------------------------------------------------------------
// Prep (R1 structure — proven fastest): one 256-thr BLOCK per output channel.
// Pack weight sign bits (bit=1 <=> w>=0, Brevitas sign(0)=+1) and per-channel
// integer popcount thresholds in double (exact sign decisions):
//   dot = K - 2p ;  layer+BN+sign == (p <= Tint[o])
// ---------------------------------------------------------------------------
__global__ __launch_bounds__(256) void bnn_prep(
    const float* __restrict__ w1, const float* __restrict__ b1, const float* __restrict__ g1,
    const float* __restrict__ be1, const float* __restrict__ m1, const float* __restrict__ v1,
    const float* __restrict__ w2, const float* __restrict__ b2, const float* __restrict__ g2,
    const float* __restrict__ be2, const float* __restrict__ m2, const float* __restrict__ v2,
    const float* __restrict__ w3, const float* __restrict__ b3, const float* __restrict__ g3,
    const float* __restrict__ be3, const float* __restrict__ m3, const float* __restrict__ v3,
    const float* __restrict__ wfc,
    uint32_t* __restrict__ ws)
{
    const int t    = threadIdx.x;
    const int lane = t & 63;
    const int wv   = t >> 6;
    const int blk  = blockIdx.x;
    __shared__ double red[4];

    if (blk < 3072) {
        const int l = blk >> 10;      // layer 0..2
        const int o = blk & 1023;     // output channel
        const float *w, *bb, *g, *be, *m, *v;
        int K; uint32_t* Wp; int* T;
        if (l == 0)      { w=w1; bb=b1; g=g1; be=be1; m=m1; v=v1; K=784;  Wp = ws + OFF_W1/4; T = (int*)(ws + OFF_T1/4); }
        else if (l == 1) { w=w2; bb=b2; g=g2; be=be2; m=m2; v=v2; K=1024; Wp = ws + OFF_W2/4; T = (int*)(ws + OFF_T2/4); }
        else             { w=w3; bb=b3; g=g3; be=be3; m=m3; v=v3; K=1024; Wp = ws + OFF_W3/4; T = (int*)(ws + OFF_T3/4); }

        const float* wr = w + (size_t)o * K;
        double s = 0.0;
        #pragma unroll
        for (int iter = 0; iter < 4; ++iter) {
            int idx = iter * 256 + t;
            bool inb = idx < K;
            float wval = inb ? wr[idx] : -1.0f;           // OOB -> bit 0 (zero pad)
            if (inb) s += fabs((double)wval);
            unsigned long long mask = __ballot(inb && (wval >= 0.0f));
            if (lane == 0)
                *(uint64_t*)(Wp + (size_t)o * 32 + iter * 8 + wv * 2) = mask;
        }
        #pragma unroll
        for (int off = 32; off > 0; off >>= 1) s += __shfl_down(s, off, 64);
        if (lane == 0) red[wv] = s;
        __syncthreads();
        if (t == 0) {
            double sum = red[0] + red[1] + red[2] + red[3];
            double scale = sum / (double)K;                      // mean|w|, > 0
            double r = (double)g[o] / sqrt((double)v[o] + 1e-5); // > 0
            // f = dot*scale*r + (b-m)*r + be >= 0  <=>  dot >= tt  <=>  p <= Td
            double tt = (((double)m[o] - (double)bb[o]) * r - (double)be[o]) / (scale * r);
            double C  = ceil(tt);                                // dot >= C (dot integer)
            double Td = floor(((double)K - C) * 0.5);
            Td = fmax(fmin(Td, 100000.0), -1.0);
            T[o] = (int)Td;
        }
    } else {
        // wfc: pack 10 rows of 1024 bits + global mean|wfc| in double
        uint32_t* Wp = ws + OFF_WFC/4;
        double s = 0.0;
        for (int rr = 0; rr < 10; ++rr) {
            const float* wr = wfc + rr * 1024;
            #pragma unroll
            for (int iter = 0; iter < 4; ++iter) {
                int idx = iter * 256 + t;
                float wval = wr[idx];
                s += fabs((double)wval);
                unsigned long long mask = __ballot(wval >= 0.0f);
                if (lane == 0)
                    *(uint64_t*)(Wp + rr * 32 + iter * 8 + wv * 2) = mask;
            }
        }
        #pragma unroll
        for (int off = 32; off > 0; off >>= 1) s += __shfl_down(s, off, 64);
        if (lane == 0) red[wv] = s;
        __syncthreads();
        if (t == 0)
            *(double*)(ws + OFF_SFC/4) = (red[0] + red[1] + red[2] + red[3]) / 10240.0;
    }
}

// ---------------------------------------------------------------------------
// Main: fully fused 3 binary layers + FC. Block = 512 thr (8 waves), RWS=8
// rows/block, grid=1024. C=2: thread t owns channels t and t+512 -> W0+W1 =
// 64 VGPRs register-resident. __launch_bounds__(512,4) -> 4 waves/SIMD ->
// 128-VGPR budget, so the compiler CAN keep W resident (R2/R3 failure: 1024-
// thr blocks made it target 8 waves/SIMD = 64-VGPR cap -> W reloaded from
// cache every row). 2 blocks/CU = 16 waves/CU (50% occ).
// Wave wv's ballots cover channels [64wv,+64) and [512+64wv,+64) -> words
// 2wv,2wv+1 and 16+2wv,17+2wv of the next bit-buffer.
// ---------------------------------------------------------------------------
__global__ __launch_bounds__(512, 4) void bnn_main(
    const float* __restrict__ x,
    const uint32_t* __restrict__ ws,
    const float* __restrict__ bfc,
    float* __restrict__ out)
{
    __shared__ alignas(16) uint32_t bufA[RWS][32];
    __shared__ alignas(16) uint32_t bufB[RWS][32];
    const int t    = threadIdx.x;       // 0..511
    const int lane = t & 63;
    const int wv   = t >> 6;            // 0..7
    const int row0 = blockIdx.x * RWS;

    // ---- pack input bits: wave wv packs row wv. +1 <=> 2x-1>=0 <=> x>=0.5 ----
    {
        const float* xr = x + (size_t)(row0 + wv) * 784;
        #pragma unroll
        for (int k = 0; k < 13; ++k) {
            const int idx = k * 64 + lane;
            const bool bit = (idx < 784) && (xr[idx] >= 0.5f);
            unsigned long long m = __ballot(bit);
            if (lane == 0) *(uint64_t*)(&bufA[wv][2 * k]) = m;
        }
        if (lane == 0) {
            *(uint64_t*)(&bufA[wv][26]) = 0ull;
            *(uint64_t*)(&bufA[wv][28]) = 0ull;
            *(uint64_t*)(&bufA[wv][30]) = 0ull;
        }
    }
    __syncthreads();

    const uint32_t* Wbase[3] = { ws + OFF_W1/4, ws + OFF_W2/4, ws + OFF_W3/4 };
    const int*      Tbase[3] = { (const int*)(ws + OFF_T1/4), (const int*)(ws + OFF_T2/4), (const int*)(ws + OFF_T3/4) };

    uint32_t (*cur)[32] = bufA;
    uint32_t (*nxt)[32] = bufB;

    const int c0 = t;           // this thread's two channels
    const int c1 = t + 512;

    for (int l = 0; l < 3; ++l) {
        uint32_t W0[32], W1[32];
        {
            const uint4* p0 = (const uint4*)(Wbase[l] + (size_t)c0 * 32);
            const uint4* p1 = (const uint4*)(Wbase[l] + (size_t)c1 * 32);
            #pragma unroll
            for (int i = 0; i < 8; ++i) { ((uint4*)W0)[i] = p0[i]; ((uint4*)W1)[i] = p1[i]; }
        }
        const int T0 = Tbase[l][c0];
        const int T1 = Tbase[l][c1];

        for (int r = 0; r < RWS; ++r) {
            uint32_t A[32];
            #pragma unroll
            for (int i = 0; i < 8; ++i) ((uint4*)A)[i] = ((const uint4*)cur[r])[i];  // broadcast
            int pa = 0, pb = 0, pc = 0, pd = 0;   // 4 chains for ILP
            #pragma unroll
            for (int i = 0; i < 16; ++i) {
                pa += __popc(A[i]      ^ W0[i]);
                pb += __popc(A[i + 16] ^ W0[i + 16]);
                pc += __popc(A[i]      ^ W1[i]);
                pd += __popc(A[i + 16] ^ W1[i + 16]);
            }
            unsigned long long m0 = __ballot((pa + pb) <= T0);
            unsigned long long m1 = __ballot((pc + pd) <= T1);
            if (lane == 0) {
                *(uint64_t*)(&nxt[r][2 * wv])      = m0;
                *(uint64_t*)(&nxt[r][16 + 2 * wv]) = m1;
            }
        }
        __syncthreads();
        uint32_t (*tmp)[32] = cur; cur = nxt; nxt = tmp;
    }

    // ---- final FC: out[b][c] = (1024-2p)*scaleFC + bfc[c], exact integer dot ----
    if (t < RWS * 10) {
        const float sfc = (float)(*(const double*)(ws + OFF_SFC/4));
        const uint32_t* Wfc = ws + OFF_WFC/4;
        const int r = t / 10, ch = t % 10;
        const uint32_t* wrow = Wfc + ch * 32;
        int p = 0;
        #pragma unroll
        for (int i = 0; i < 32; ++i) p += __popc(cur[r][i] ^ wrow[i]);
        const int s = 1024 - 2 * p;
        out[(size_t)(row0 + r) * 10 + ch] = (float)s * sfc + bfc[ch];
    }
}

extern "C" void kernel_launch(void* const* d_in, const int* in_sizes, int n_in,
                              void* d_out, int out_size, void* d_ws, size_t ws_size,
                              hipStream_t stream) {
    const float* x   = (const float*)d_in[0];
    const float* w1  = (const float*)d_in[1];
    const float* b1  = (const float*)d_in[2];
    const float* g1  = (const float*)d_in[3];
    const float* be1 = (const float*)d_in[4];
    const float* m1  = (const float*)d_in[5];
    const float* v1  = (const float*)d_in[6];
    const float* w2  = (const float*)d_in[7];
    const float* b2  = (const float*)d_in[8];
    const float* g2  = (const float*)d_in[9];
    const float* be2 = (const float*)d_in[10];
    const float* m2  = (const float*)d_in[11];
    const float* v2  = (const float*)d_in[12];
    const float* w3  = (const float*)d_in[13];
    const float* b3  = (const float*)d_in[14];
    const float* g3  = (const float*)d_in[15];
    const float* be3 = (const float*)d_in[16];
    const float* m3  = (const float*)d_in[17];
    const float* v3  = (const float*)d_in[18];
    const float* wfc = (const float*)d_in[19];
    const float* bfc = (const float*)d_in[20];
    uint32_t* ws = (uint32_t*)d_ws;
    float* out = (float*)d_out;

    bnn_prep<<<3073, 256, 0, stream>>>(w1, b1, g1, be1, m1, v1,
                                       w2, b2, g2, be2, m2, v2,
                                       w3, b3, g3, be3, m3, v3,
                                       wfc, ws);
    bnn_main<<<8192 / RWS, 512, 0, stream>>>(x, ws, bfc, out);
}